// Round 5
// baseline (399.337 us; speedup 1.0000x reference)
//
#include <hip/hip_runtime.h>
#include <hip/hip_fp16.h>

// Reblur_Net: 3 recurrent modulated DCNv2 passes, C=O=3, K=3, B=4, H=W=512.
// out = (sharp + f1 + f2 + f3) / 4.
//
// Features as half4 (8 B/px). Motion strip DMA'd to LDS (global_load_lds).
// Feature tile (10 rows x 266 cols, +-4/+-5 halo) staged in LDS; bilinear
// taps read LDS (both corners of a row = adjacent 8B px); rare out-of-halo
// samples take the exact global-gather fallback. Final average folded into
// pass 3 (no per-pass out RMW).

#define HH 512
#define WW 512
#define BATCH 4
#define HWSZ (HH * WW)

#define TROWS 10
#define TCOLS 266
#define TPITCH 272
#define HALO_Y 4
#define HALO_X 5

union U4 { uint4 u; __half2 h[4]; };
union U2 { uint2 u; __half2 h[2]; };

typedef const __attribute__((address_space(1))) void* gas_t;
typedef __attribute__((address_space(3))) void* las_t;

__global__ __launch_bounds__(256) void to_half_kernel(
    const float* __restrict__ sharp, uint4* __restrict__ dst)
{
    const int i = blockIdx.x * 256 + threadIdx.x;   // pair index over B*HWSZ/2
    const int b = i >> 17;
    const int p = (i & (HWSZ / 2 - 1)) * 2;
    const float* s = sharp + (size_t)b * 3 * HWSZ + p;
    const float2 c0 = *(const float2*)(s);
    const float2 c1 = *(const float2*)(s + HWSZ);
    const float2 c2 = *(const float2*)(s + 2 * HWSZ);
    U4 o;
    o.h[0] = __float22half2_rn(make_float2(c0.x, c1.x));
    o.h[1] = __float22half2_rn(make_float2(c2.x, 0.f));
    o.h[2] = __float22half2_rn(make_float2(c0.y, c1.y));
    o.h[3] = __float22half2_rn(make_float2(c2.y, 0.f));
    dst[i] = o.u;
}

template <bool LAST>
__global__ __launch_bounds__(256, 3) void dcn_kernel(
    const uint2* __restrict__ src,     // [B][HWSZ] half4 px (current features)
    const float* __restrict__ motion,  // [B,27,H,W]
    const float* __restrict__ wgt,     // 81 floats [o][c][k]
    const float* __restrict__ bias,    // 3 floats
    uint2* __restrict__ dst,           // half4 px (if !LAST)
    const uint2* __restrict__ cS,      // sharp half4 (if LAST)
    const uint2* __restrict__ c1,      // f1 half4 (if LAST)
    float* __restrict__ out)           // [B,3,H,W] planar fp32 (if LAST)
{
    __shared__ float mlds[27][256];          // 27648 B
    __shared__ U2 tile[TROWS * TPITCH];      // 21760 B
    __shared__ float sw[84];

    const int t = threadIdx.x;
    const int blk = blockIdx.x;              // 4096
    const int b = blk >> 10;
    const int pbase = (blk & 1023) * 256;    // strip start within image
    const int y = pbase >> 9;
    const int xbase = pbase & 511;           // 0 or 256
    const int x = xbase + t;
    const int p = pbase + t;

    if (t < 84) sw[t] = (t < 81) ? wgt[t] : bias[t - 81];

    // Async DMA: motion planes for this strip -> mlds (one wave per plane).
    {
        const int w = t >> 6, lane = t & 63;
        const float* mbase = motion + (size_t)b * 27 * HWSZ + pbase;
#pragma unroll
        for (int r = 0; r < 7; ++r) {
            const int plane = r * 4 + w;
            if (plane < 27) {
                const float* gsrc = mbase + (size_t)plane * HWSZ + lane * 4;
                __builtin_amdgcn_global_load_lds((gas_t)gsrc,
                                                 (las_t)&mlds[plane][0],
                                                 16, 0, 0);
            }
        }
    }

    const uint2* simg = src + (size_t)b * HWSZ;

    // Stage feature tile rows y-4..y+5, cols xbase-5..xbase+260 (valid only).
#pragma unroll
    for (int tr = 0; tr < TROWS; ++tr) {
        const int gy = y - HALO_Y + tr;
        if (gy >= 0 && gy < HH) {
            int gx = xbase - HALO_X + t;
            if (gx >= 0 && gx < WW)
                tile[tr * TPITCH + t] = *(const U2*)&simg[gy * WW + gx];
            if (t < TCOLS - 256) {
                gx = xbase - HALO_X + 256 + t;
                if (gx < WW)
                    tile[tr * TPITCH + 256 + t] = *(const U2*)&simg[gy * WW + gx];
            }
        }
    }

    // Pass-3 center values (issued before the barrier to hide latency).
    U2 csv, c1v, c2v;
    if (LAST) {
        csv = *(const U2*)&cS[(size_t)b * HWSZ + p];
        c1v = *(const U2*)&c1[(size_t)b * HWSZ + p];
        c2v = *(const U2*)&simg[p];
    }

    __syncthreads();   // drains DMA (vmcnt) + ds_writes

    float acc0 = sw[81], acc1 = sw[82], acc2 = sw[83];

#pragma unroll
    for (int k = 0; k < 9; ++k) {
        const float dy = mlds[2 * k][t];
        const float dx = mlds[2 * k + 1][t];
        const float m  = mlds[18 + k][t];
        const float py = (float)(y + k / 3 - 1) + dy;
        const float px = (float)(x + k % 3 - 1) + dx;

        const float y0f = floorf(py), x0f = floorf(px);
        const float wy = py - y0f, wx = px - x0f;
        const bool vy0 = (y0f >= 0.f) && (y0f <= 511.f);
        const bool vy1 = (y0f >= -1.f) && (y0f <= 510.f);
        const bool vx0 = (x0f >= 0.f) && (x0f <= 511.f);
        const bool vx1 = (x0f >= -1.f) && (x0f <= 510.f);
        const int iy0 = (int)fminf(fmaxf(y0f, 0.f), 511.f);
        const int iy1 = (int)fminf(fmaxf(y0f + 1.f, 0.f), 511.f);
        const int ix0 = (int)fminf(fmaxf(x0f, 0.f), 511.f);
        const int ix1 = (int)fminf(fmaxf(x0f + 1.f, 0.f), 511.f);
        const int lc  = (int)fminf(fmaxf(x0f, 0.f), 510.f);
        const int s0 = ix0 - lc, s1 = ix1 - lc;

        const float w00 = (vy0 && vx0) ? (1.f - wy) * (1.f - wx) * m : 0.f;
        const float w01 = (vy0 && vx1) ? (1.f - wy) * wx * m : 0.f;
        const float w10 = (vy1 && vx0) ? wy * (1.f - wx) * m : 0.f;
        const float w11 = (vy1 && vx1) ? wy * wx * m : 0.f;
        const float wlo0 = s0 ? 0.f : (s1 ? w00 : w00 + w01);
        const float whi0 = s1 ? (s0 ? w00 + w01 : w01) : 0.f;
        const float wlo1 = s0 ? 0.f : (s1 ? w10 : w10 + w11);
        const float whi1 = s1 ? (s0 ? w10 + w11 : w11) : 0.f;

        U2 aL, aH, bL, bH;
        const bool fast = (iy0 >= y - HALO_Y) && (iy1 <= y - HALO_Y + TROWS - 1) &&
                          (lc >= xbase - HALO_X) && (lc <= xbase - HALO_X + TCOLS - 2);
        if (fast) {
            const int ta = (iy0 - (y - HALO_Y)) * TPITCH + (lc - (xbase - HALO_X));
            const int tb = (iy1 - (y - HALO_Y)) * TPITCH + (lc - (xbase - HALO_X));
            aL = tile[ta]; aH = tile[ta + 1];
            bL = tile[tb]; bH = tile[tb + 1];
        } else {
            const char* sb = (const char*)simg;
            U4 ra, rb;
            ra.u = *(const uint4*)(sb + (size_t)(iy0 * WW + lc) * 8);
            rb.u = *(const uint4*)(sb + (size_t)(iy1 * WW + lc) * 8);
            aL.h[0] = ra.h[0]; aL.h[1] = ra.h[1];
            aH.h[0] = ra.h[2]; aH.h[1] = ra.h[3];
            bL.h[0] = rb.h[0]; bL.h[1] = rb.h[1];
            bH.h[0] = rb.h[2]; bH.h[1] = rb.h[3];
        }

        const float2 aL01 = __half22float2(aL.h[0]);
        const float2 aL2  = __half22float2(aL.h[1]);
        const float2 aH01 = __half22float2(aH.h[0]);
        const float2 aH2  = __half22float2(aH.h[1]);
        const float2 bL01 = __half22float2(bL.h[0]);
        const float2 bL2  = __half22float2(bL.h[1]);
        const float2 bH01 = __half22float2(bH.h[0]);
        const float2 bH2  = __half22float2(bH.h[1]);

        const float v0 = wlo0 * aL01.x + whi0 * aH01.x + wlo1 * bL01.x + whi1 * bH01.x;
        const float v1 = wlo0 * aL01.y + whi0 * aH01.y + wlo1 * bL01.y + whi1 * bH01.y;
        const float v2 = wlo0 * aL2.x  + whi0 * aH2.x  + wlo1 * bL2.x  + whi1 * bH2.x;

        acc0 += sw[0 * 9 + k] * v0 + sw[1 * 9 + k] * v1 + sw[2 * 9 + k] * v2;
        acc1 += sw[3 * 9 + k] * v0 + sw[4 * 9 + k] * v1 + sw[5 * 9 + k] * v2;
        acc2 += sw[6 * 9 + k] * v0 + sw[7 * 9 + k] * v1 + sw[8 * 9 + k] * v2;
    }

    if (!LAST) {
        U2 o;
        o.h[0] = __float22half2_rn(make_float2(acc0, acc1));
        o.h[1] = __float22half2_rn(make_float2(acc2, 0.f));
        dst[(size_t)b * HWSZ + p] = o.u;
    } else {
        const float2 s01 = __half22float2(csv.h[0]);
        const float2 s2  = __half22float2(csv.h[1]);
        const float2 a01 = __half22float2(c1v.h[0]);
        const float2 a2  = __half22float2(c1v.h[1]);
        const float2 b01 = __half22float2(c2v.h[0]);
        const float2 b2  = __half22float2(c2v.h[1]);
        const size_t ob = (size_t)b * 3 * HWSZ + p;
        out[ob]             = (s01.x + a01.x + b01.x + acc0) * 0.25f;
        out[ob + HWSZ]      = (s01.y + a01.y + b01.y + acc1) * 0.25f;
        out[ob + 2 * HWSZ]  = (s2.x  + a2.x  + b2.x  + acc2) * 0.25f;
    }
}

extern "C" void kernel_launch(void* const* d_in, const int* in_sizes, int n_in,
                              void* d_out, int out_size, void* d_ws, size_t ws_size,
                              hipStream_t stream) {
    const float* sharp  = (const float*)d_in[0];
    const float* motion = (const float*)d_in[1];
    const float* wts    = (const float*)d_in[2];  // 3 x 81
    const float* bias   = (const float*)d_in[3];  // 3 x 3
    float* out = (float*)d_out;

    const size_t img = (size_t)BATCH * HWSZ;
    uint2* bufS = (uint2*)d_ws;          // 8.39 MB each, 25.2 MB total
    uint2* buf1 = bufS + img;
    uint2* buf2 = buf1 + img;

    const dim3 block(256);
    const dim3 gridT(img / 512);         // 2048 (pair kernel)
    const dim3 gridD(img / 256);         // 4096

    to_half_kernel<<<gridT, block, 0, stream>>>(sharp, (uint4*)bufS);
    dcn_kernel<false><<<gridD, block, 0, stream>>>(
        bufS, motion, wts, bias, buf1, nullptr, nullptr, nullptr);
    dcn_kernel<false><<<gridD, block, 0, stream>>>(
        buf1, motion, wts + 81, bias + 3, buf2, nullptr, nullptr, nullptr);
    dcn_kernel<true><<<gridD, block, 0, stream>>>(
        buf2, motion, wts + 162, bias + 6, nullptr, bufS, buf1, out);
}

// Round 6
// 117.261 us; speedup vs baseline: 3.4056x; 3.4056x over previous
//
#include <hip/hip_runtime.h>
#include <hip/hip_fp16.h>

// Reblur_Net: 3 recurrent modulated DCNv2 passes, C=O=3, K=3, B=4, H=W=512.
// out = (sharp + f1 + f2 + f3) / 4.
//
// R4 structure (motion strip DMA'd to LDS via global_load_lds, half4 feature
// gathers: both corners of a bilinear row = one 16B dwordx4). New in R6:
//  - pass 1 repacks its LDS motion strip to planar fp16 (free: data is already
//    in LDS); passes 2-3 DMA half-size fp16 motion strips.
//  - final 4-way average folded into pass 3 (no per-pass out RMW).

#define HH 512
#define WW 512
#define BATCH 4
#define HWSZ (HH * WW)
#define MP 28   // fp16 motion plane stride (27 used + 1 pad so DMA pairs are unmasked)

union U4 { uint4 u; __half2 h[4]; };
union U2 { uint2 u; __half2 h[2]; };

typedef const __attribute__((address_space(1))) void* gas_t;
typedef __attribute__((address_space(3))) void* las_t;

__global__ __launch_bounds__(256) void to_half_kernel(
    const float* __restrict__ sharp, uint4* __restrict__ dst)
{
    const int i = blockIdx.x * 256 + threadIdx.x;   // pair index over B*HWSZ/2
    const int b = i >> 17;
    const int p = (i & (HWSZ / 2 - 1)) * 2;
    const float* s = sharp + (size_t)b * 3 * HWSZ + p;
    const float2 c0 = *(const float2*)(s);
    const float2 c1 = *(const float2*)(s + HWSZ);
    const float2 c2 = *(const float2*)(s + 2 * HWSZ);
    U4 o;
    o.h[0] = __float22half2_rn(make_float2(c0.x, c1.x));
    o.h[1] = __float22half2_rn(make_float2(c2.x, 0.f));
    o.h[2] = __float22half2_rn(make_float2(c0.y, c1.y));
    o.h[3] = __float22half2_rn(make_float2(c2.y, 0.f));
    dst[i] = o.u;
}

// Bilinear sample of 3 channels at (py,px), modulation m, zero outside.
__device__ __forceinline__ void bilinear3(const char* __restrict__ sb,
                                          float py, float px, float m,
                                          float& o0, float& o1, float& o2)
{
    const float y0f = floorf(py), x0f = floorf(px);
    const float wy = py - y0f, wx = px - x0f;
    const bool vy0 = (y0f >= 0.f) && (y0f <= 511.f);
    const bool vy1 = (y0f >= -1.f) && (y0f <= 510.f);
    const bool vx0 = (x0f >= 0.f) && (x0f <= 511.f);
    const bool vx1 = (x0f >= -1.f) && (x0f <= 510.f);
    const int iy0 = (int)fminf(fmaxf(y0f, 0.f), 511.f);
    const int iy1 = (int)fminf(fmaxf(y0f + 1.f, 0.f), 511.f);
    const int ix0 = (int)fminf(fmaxf(x0f, 0.f), 511.f);
    const int ix1 = (int)fminf(fmaxf(x0f + 1.f, 0.f), 511.f);
    const int lc  = (int)fminf(fmaxf(x0f, 0.f), 510.f);   // pair base column
    const int s0 = ix0 - lc;
    const int s1 = ix1 - lc;

    const float w00 = (vy0 && vx0) ? (1.f - wy) * (1.f - wx) * m : 0.f;
    const float w01 = (vy0 && vx1) ? (1.f - wy) * wx * m : 0.f;
    const float w10 = (vy1 && vx0) ? wy * (1.f - wx) * m : 0.f;
    const float w11 = (vy1 && vx1) ? wy * wx * m : 0.f;

    // Blend corner weights onto the two loaded pixel slots (clamp-safe).
    const float wlo0 = s0 ? 0.f : (s1 ? w00 : w00 + w01);
    const float whi0 = s1 ? (s0 ? w00 + w01 : w01) : 0.f;
    const float wlo1 = s0 ? 0.f : (s1 ? w10 : w10 + w11);
    const float whi1 = s1 ? (s0 ? w10 + w11 : w11) : 0.f;

    U4 ra, rb;
    ra.u = *(const uint4*)(sb + (size_t)(iy0 * WW + lc) * 8);
    rb.u = *(const uint4*)(sb + (size_t)(iy1 * WW + lc) * 8);
    const float2 aL = __half22float2(ra.h[0]);
    const float2 aLz = __half22float2(ra.h[1]);
    const float2 aH = __half22float2(ra.h[2]);
    const float2 aHz = __half22float2(ra.h[3]);
    const float2 bL = __half22float2(rb.h[0]);
    const float2 bLz = __half22float2(rb.h[1]);
    const float2 bH = __half22float2(rb.h[2]);
    const float2 bHz = __half22float2(rb.h[3]);

    o0 = wlo0 * aL.x + whi0 * aH.x + wlo1 * bL.x + whi1 * bH.x;
    o1 = wlo0 * aL.y + whi0 * aH.y + wlo1 * bL.y + whi1 * bH.y;
    o2 = wlo0 * aLz.x + whi0 * aHz.x + wlo1 * bLz.x + whi1 * bHz.x;
}

// FP16MOT: motion comes from the fp16 planar repack (passes 2,3).
// REPACK : write the LDS fp32 motion strip back out as fp16 (pass 1).
// LAST   : fold out = (sharp + f1 + f2 + f3)/4 (pass 3).
template <bool FP16MOT, bool REPACK, bool LAST>
__global__ __launch_bounds__(256) void dcn_kernel(
    const uint2* __restrict__ src,     // [B][HWSZ] half4 px (current features)
    const float* __restrict__ motion,  // [B,27,H,W] fp32 (if !FP16MOT)
    __half* __restrict__ mot16,        // [B,MP,H,W] fp16 (out if REPACK, in if FP16MOT)
    const float* __restrict__ wgt,     // 81 floats [o][c][k]
    const float* __restrict__ bias,    // 3 floats
    uint2* __restrict__ dst,           // half4 px (if !LAST)
    const uint2* __restrict__ cS,      // sharp half4 (if LAST)
    const uint2* __restrict__ c1,      // f1 half4 (if LAST)
    float* __restrict__ out)           // [B,3,H,W] planar fp32 (if LAST)
{
    __shared__ __align__(16) char msmem[FP16MOT ? MP * 256 * 2 : 27 * 256 * 4];
    __shared__ float sw[84];

    const int t = threadIdx.x;
    const int blk = blockIdx.x;              // 4096
    const int b = blk >> 10;
    const int pbase = (blk & 1023) * 256;    // strip start within image
    const int y = pbase >> 9;
    const int x = (pbase & 511) + t;
    const int p = pbase + t;
    const int w = t >> 6, lane = t & 63;

    if (t < 84) sw[t] = (t < 81) ? wgt[t] : bias[t - 81];

    // Async DMA: motion strip -> LDS.
    if (!FP16MOT) {
        // fp32: one wave per plane, 64 lanes x 16B = 1024B (256 floats).
        const float* mbase = motion + (size_t)b * 27 * HWSZ + pbase;
#pragma unroll
        for (int r = 0; r < 7; ++r) {
            const int pl = r * 4 + w;
            if (pl < 27) {
                const float* gsrc = mbase + (size_t)pl * HWSZ + lane * 4;
                __builtin_amdgcn_global_load_lds((gas_t)gsrc,
                                                 (las_t)(msmem + pl * 1024),
                                                 16, 0, 0);
            }
        }
    } else {
        // fp16: one wave per PLANE PAIR (2 x 512B = 1024B LDS, contiguous).
        // Global src is per-lane: lanes 0..31 -> plane 2q, lanes 32..63 -> 2q+1.
        // Pair q=13 touches pad plane 27 (allocated, never read).
        const __half* mbase = mot16 + (size_t)b * MP * HWSZ + pbase;
#pragma unroll
        for (int r = 0; r < 4; ++r) {
            const int q = r * 4 + w;
            if (q < 14) {
                const int pl = 2 * q + (lane >> 5);
                const __half* gsrc = mbase + (size_t)pl * HWSZ + (lane & 31) * 8;
                __builtin_amdgcn_global_load_lds((gas_t)gsrc,
                                                 (las_t)(msmem + q * 1024),
                                                 16, 0, 0);
            }
        }
    }

    const uint2* simg = src + (size_t)b * HWSZ;

    // Pass-3 center values (issued before the barrier to hide latency).
    U2 csv, c1v, c2v;
    if (LAST) {
        csv = *(const U2*)&cS[(size_t)b * HWSZ + p];
        c1v = *(const U2*)&c1[(size_t)b * HWSZ + p];
        c2v = *(const U2*)&simg[p];
    }

    __syncthreads();   // drains DMA (vmcnt+lgkmcnt)

    // Pass 1: repack the fp32 strip (already in LDS) to planar fp16.
    if (REPACK) {
        __half* obase = mot16 + (size_t)b * MP * HWSZ + pbase;
        const float* mf = (const float*)msmem;
#pragma unroll
        for (int r = 0; r < 7; ++r) {
            const int pl = r * 4 + w;
            if (pl < 27) {
                const float4 v = *(const float4*)&mf[pl * 256 + lane * 4];
                U2 o;
                o.h[0] = __float22half2_rn(make_float2(v.x, v.y));
                o.h[1] = __float22half2_rn(make_float2(v.z, v.w));
                *(uint2*)(obase + (size_t)pl * HWSZ + lane * 4) = o.u;
            }
        }
    }

    const char* sb = (const char*)simg;
    float acc0 = sw[81], acc1 = sw[82], acc2 = sw[83];

#pragma unroll
    for (int k = 0; k < 9; ++k) {
        float dy, dx, m;
        if (!FP16MOT) {
            const float* mf = (const float*)msmem;
            dy = mf[(2 * k) * 256 + t];
            dx = mf[(2 * k + 1) * 256 + t];
            m  = mf[(18 + k) * 256 + t];
        } else {
            const __half* mh = (const __half*)msmem;
            dy = __half2float(mh[(2 * k) * 256 + t]);
            dx = __half2float(mh[(2 * k + 1) * 256 + t]);
            m  = __half2float(mh[(18 + k) * 256 + t]);
        }
        const float py = (float)(y + k / 3 - 1) + dy;
        const float px = (float)(x + k % 3 - 1) + dx;

        float v0, v1, v2;
        bilinear3(sb, py, px, m, v0, v1, v2);
        acc0 += sw[0 * 9 + k] * v0 + sw[1 * 9 + k] * v1 + sw[2 * 9 + k] * v2;
        acc1 += sw[3 * 9 + k] * v0 + sw[4 * 9 + k] * v1 + sw[5 * 9 + k] * v2;
        acc2 += sw[6 * 9 + k] * v0 + sw[7 * 9 + k] * v1 + sw[8 * 9 + k] * v2;
    }

    if (!LAST) {
        U2 o;
        o.h[0] = __float22half2_rn(make_float2(acc0, acc1));
        o.h[1] = __float22half2_rn(make_float2(acc2, 0.f));
        dst[(size_t)b * HWSZ + p] = o.u;
    } else {
        const float2 s01 = __half22float2(csv.h[0]);
        const float2 s2  = __half22float2(csv.h[1]);
        const float2 a01 = __half22float2(c1v.h[0]);
        const float2 a2  = __half22float2(c1v.h[1]);
        const float2 b01 = __half22float2(c2v.h[0]);
        const float2 b2  = __half22float2(c2v.h[1]);
        const size_t ob = (size_t)b * 3 * HWSZ + p;
        out[ob]            = (s01.x + a01.x + b01.x + acc0) * 0.25f;
        out[ob + HWSZ]     = (s01.y + a01.y + b01.y + acc1) * 0.25f;
        out[ob + 2 * HWSZ] = (s2.x  + a2.x  + b2.x  + acc2) * 0.25f;
    }
}

extern "C" void kernel_launch(void* const* d_in, const int* in_sizes, int n_in,
                              void* d_out, int out_size, void* d_ws, size_t ws_size,
                              hipStream_t stream) {
    const float* sharp  = (const float*)d_in[0];
    const float* motion = (const float*)d_in[1];
    const float* wts    = (const float*)d_in[2];  // 3 x 81
    const float* bias   = (const float*)d_in[3];  // 3 x 3
    float* out = (float*)d_out;

    const size_t img = (size_t)BATCH * HWSZ;
    uint2* bufS = (uint2*)d_ws;                   // 8.39 MB each
    uint2* buf1 = bufS + img;
    uint2* buf2 = buf1 + img;
    __half* mot16 = (__half*)(buf2 + img);        // 58.7 MB ([B][28][HW])

    const dim3 block(256);
    const dim3 gridT(img / 512);                  // 2048 (pair kernel)
    const dim3 gridD(img / 256);                  // 4096

    to_half_kernel<<<gridT, block, 0, stream>>>(sharp, (uint4*)bufS);
    // pass 1: fp32 motion in, repack fp16 motion out, f1 -> buf1
    dcn_kernel<false, true, false><<<gridD, block, 0, stream>>>(
        bufS, motion, mot16, wts, bias, buf1, nullptr, nullptr, nullptr);
    // pass 2: fp16 motion, f2 -> buf2
    dcn_kernel<true, false, false><<<gridD, block, 0, stream>>>(
        buf1, nullptr, mot16, wts + 81, bias + 3, buf2, nullptr, nullptr, nullptr);
    // pass 3: fp16 motion, fold average, write out
    dcn_kernel<true, false, true><<<gridD, block, 0, stream>>>(
        buf2, nullptr, mot16, wts + 162, bias + 6, nullptr, bufS, buf1, out);
}